// Round 1
// baseline (1022.193 us; speedup 1.0000x reference)
//
#include <hip/hip_runtime.h>
#include <hip/hip_bf16.h>

// ---- problem constants ----
#define B_   128
#define T_   17
#define E_   512
#define H_   512
#define V_   32000
#define D2_  1024
#define MR_  (B_*T_)   // 2176 rows, all divisible by 128 (17*128)

typedef __attribute__((ext_vector_type(8))) short short8;   // 8 bf16 in 4 VGPRs
typedef __attribute__((ext_vector_type(4))) float f32x4;

__device__ __forceinline__ unsigned short f2b(float f) {   // fp32 -> bf16 RNE
  unsigned u = __float_as_uint(f);
  u += 0x7FFFu + ((u >> 16) & 1u);
  return (unsigned short)(u >> 16);
}

// async global->LDS, 16B per lane. LDS dest is wave-uniform base + lane*16.
__device__ __forceinline__ void async16(const void* g, void* l) {
  __builtin_amdgcn_global_load_lds((const __attribute__((address_space(1))) unsigned int*)g,
                                   (__attribute__((address_space(3))) unsigned int*)l,
                                   16, 0, 0);
}

// ---------------------------------------------------------------------------
// bf16 MFMA GEMM: C[M x N] = A[M x K] * Bt[N x K]^T (+ epilogue)
// 128x128 block tile, 256 thr = 4 waves (2x2), each wave 64x64 = 4x4 MFMA tiles.
// BK=32. LDS chunk position XOR-swizzled by (row&3) to spread ds_read banks;
// swizzle absorbed into the *global* address so global_load_lds stays linear.
// EPI: 0 = f32 +bias0+bias1 (gates G)   1 = f32 plain (lin)
//      2 = bf16 relu(+bias0) (outb)     3 = f32 +bias0 (logits)
// ---------------------------------------------------------------------------
template<int EPI>
__global__ __launch_bounds__(256, 2)
void gemm_bt(const unsigned short* __restrict__ A,
             const unsigned short* __restrict__ Bt,
             void* __restrict__ C,
             const float* __restrict__ bias0,
             const float* __restrict__ bias1,
             int N, int K)
{
  __shared__ unsigned short sA[128 * 32];
  __shared__ unsigned short sB[128 * 32];

  const int tid  = threadIdx.x;
  const int lane = tid & 63;
  const int wave = tid >> 6;
  const int wm   = wave & 1;
  const int wn   = wave >> 1;
  const size_t bm = (size_t)blockIdx.y * 128;
  const size_t bn = (size_t)blockIdx.x * 128;

  // staging: each wave fills rows [wave*32, wave*32+32) of both tiles,
  // 2 instructions per tile (16 rows each), 16B per lane.
  const int sRow   = wave * 32 + (lane >> 2);
  const int cpos   = lane & 3;                 // LDS chunk position (linear)
  const int gchunk = cpos ^ (sRow & 3);        // which global chunk lands there

  const unsigned short* gA  = A  + (bm + sRow)      * (size_t)K + gchunk * 8;
  const unsigned short* gA2 = A  + (bm + sRow + 16) * (size_t)K + gchunk * 8;
  const unsigned short* gB  = Bt + (bn + sRow)      * (size_t)K + gchunk * 8;
  const unsigned short* gB2 = Bt + (bn + sRow + 16) * (size_t)K + gchunk * 8;

  unsigned short* lA  = &sA[wave * 1024];        // wave-uniform LDS bases
  unsigned short* lA2 = &sA[wave * 1024 + 512];
  unsigned short* lB  = &sB[wave * 1024];
  unsigned short* lB2 = &sB[wave * 1024 + 512];

  f32x4 acc[4][4] = {};

  const int fm = lane & 15;   // row within 16-tile
  const int q  = lane >> 4;   // k-chunk 0..3

  for (int kt = 0; kt < K; kt += 32) {
    async16(gA  + kt, lA);
    async16(gA2 + kt, lA2);
    async16(gB  + kt, lB);
    async16(gB2 + kt, lB2);
    __syncthreads();   // drains vmcnt then barrier

    short8 af[4], bfv[4];
#pragma unroll
    for (int i = 0; i < 4; i++) {
      int ra = wm * 64 + i * 16 + fm;
      af[i]  = *(const short8*)&sA[ra * 32 + ((q ^ (ra & 3)) * 8)];
      int rb = wn * 64 + i * 16 + fm;
      bfv[i] = *(const short8*)&sB[rb * 32 + ((q ^ (rb & 3)) * 8)];
    }
#pragma unroll
    for (int i = 0; i < 4; i++)
#pragma unroll
      for (int j = 0; j < 4; j++)
        acc[i][j] = __builtin_amdgcn_mfma_f32_16x16x32_bf16(af[i], bfv[j], acc[i][j], 0, 0, 0);
    __syncthreads();
  }

  // epilogue: C/D layout col = lane&15, row = (lane>>4)*4 + reg  [m89-verified]
#pragma unroll
  for (int i = 0; i < 4; i++) {
#pragma unroll
    for (int j = 0; j < 4; j++) {
      size_t col = bn + wn * 64 + j * 16 + fm;
      float bv = 0.f;
      if constexpr (EPI == 0) bv = bias0[col] + bias1[col];
      if constexpr (EPI == 2 || EPI == 3) bv = bias0[col];
#pragma unroll
      for (int r = 0; r < 4; r++) {
        size_t row = bm + wm * 64 + i * 16 + q * 4 + r;
        float v = acc[i][j][r] + bv;
        if constexpr (EPI == 2) {
          v = v > 0.f ? v : 0.f;
          ((unsigned short*)C)[row * N + col] = f2b(v);
        } else {
          ((float*)C)[row * N + col] = v;
        }
      }
    }
  }
}

// ---- fp32 -> bf16 elementwise (vec4) ----
__global__ void cvt_bf16(const float* __restrict__ src, unsigned short* __restrict__ dst, int n4) {
  int i = blockIdx.x * 256 + threadIdx.x;
  if (i >= n4) return;
  float4 v = ((const float4*)src)[i];
  ushort4 o;
  o.x = f2b(v.x); o.y = f2b(v.y); o.z = f2b(v.z); o.w = f2b(v.w);
  ((ushort4*)dst)[i] = o;
}

// ---- fp32 KxN -> bf16 NxK transpose+convert, 32x32 LDS tiles ----
__global__ void transpose_cvt(const float* __restrict__ src, unsigned short* __restrict__ dst,
                              int K, int N) {
  __shared__ float tile[32][33];
  int n0 = blockIdx.x * 32, k0 = blockIdx.y * 32;
  int tcol = threadIdx.x & 31, trow = threadIdx.x >> 5;  // 32 x 8
  for (int r = trow; r < 32; r += 8)
    tile[r][tcol] = src[(size_t)(k0 + r) * N + n0 + tcol];
  __syncthreads();
  for (int r = trow; r < 32; r += 8)
    dst[(size_t)(n0 + r) * K + k0 + tcol] = f2b(tile[tcol][r]);
}

// ---- encoder: xb[row b] = bf16(features[b] @ W_enc + b_enc) (time-major t=0) ----
__global__ __launch_bounds__(256) void encode(const float* __restrict__ features,
                                              const float* __restrict__ W_enc,
                                              const float* __restrict__ b_enc,
                                              unsigned short* __restrict__ xb) {
  __shared__ float fs[512];
  int b = blockIdx.y, e = blockIdx.x * 256 + threadIdx.x;
  fs[threadIdx.x]       = features[b * 512 + threadIdx.x];
  fs[threadIdx.x + 256] = features[b * 512 + threadIdx.x + 256];
  __syncthreads();
  float acc = 0.f;
#pragma unroll 8
  for (int k = 0; k < 512; k++) acc += fs[k] * W_enc[(size_t)k * 512 + e];
  xb[(size_t)b * 512 + e] = f2b(acc + b_enc[e]);
}

// ---- embedding gather: xb[t*128+b] = bf16(emb[captions[b][t-1]]), t=1..16 ----
__global__ void embed_k(const int* __restrict__ captions, const float* __restrict__ emb,
                        unsigned short* __restrict__ xb) {
  int t = blockIdx.x + 1, b = blockIdx.y;
  int tok = captions[b * T_ + (t - 1)];
  float4 v = ((const float4*)(emb + (size_t)tok * 512))[threadIdx.x];
  ushort4 o;
  o.x = f2b(v.x); o.y = f2b(v.y); o.z = f2b(v.z); o.w = f2b(v.w);
  ((ushort4*)(xb + (size_t)(t * B_ + b) * 512))[threadIdx.x] = o;
}

// ---- LSTM pointwise: gates = G[t] (+ lin), update c,h; h -> hb (bf16) + hsb (b-major) ----
__global__ void lstm_point(const float* __restrict__ Gt, const float* __restrict__ lin,
                           float* __restrict__ c, unsigned short* __restrict__ hb,
                           unsigned short* __restrict__ hsb, int t, int has_lin) {
  int idx = blockIdx.x * 256 + threadIdx.x;   // 128*512
  int b = idx >> 9, j = idx & 511;
  const float* g = Gt + (size_t)b * 2048;
  float gi = g[j], gf = g[512 + j], gg = g[1024 + j], go = g[1536 + j];
  if (has_lin) {
    const float* l = lin + (size_t)b * 2048;
    gi += l[j]; gf += l[512 + j]; gg += l[1024 + j]; go += l[1536 + j];
  }
  float ii = 1.f / (1.f + __expf(-gi));
  float ff = 1.f / (1.f + __expf(-gf));
  float oo = 1.f / (1.f + __expf(-go));
  float gt = tanhf(gg);
  float cprev = has_lin ? c[idx] : 0.f;
  float cn = ff * cprev + ii * gt;
  float hn = oo * tanhf(cn);
  c[idx] = cn;
  unsigned short h16 = f2b(hn);
  hb[idx] = h16;
  hsb[((size_t)b * T_ + t) * 512 + j] = h16;   // b-major rows -> matches d_out rows
}

// ---- softmax over V per row, register-resident (32 vals/thread, 1024 thr) ----
__global__ __launch_bounds__(1024) void softmax_k(float* __restrict__ out) {
  __shared__ float ps[1024];
  float* r = out + (size_t)blockIdx.x * V_;
  int tid = threadIdx.x;
  float v[32];
  float s = 0.f;
#pragma unroll
  for (int u = 0; u < 32; u++) {
    int i = u * 1024 + tid;
    if (i < V_) { float e = __expf(r[i]); v[u] = e; s += e; }
  }
  ps[tid] = s;
  __syncthreads();
  for (int o = 512; o > 0; o >>= 1) {
    if (tid < o) ps[tid] += ps[tid + o];
    __syncthreads();
  }
  float inv = 1.f / ps[0];
#pragma unroll
  for (int u = 0; u < 32; u++) {
    int i = u * 1024 + tid;
    if (i < V_) r[i] = v[u] * inv;
  }
}

extern "C" void kernel_launch(void* const* d_in, const int* in_sizes, int n_in,
                              void* d_out, int out_size, void* d_ws, size_t ws_size,
                              hipStream_t stream) {
  const float* features = (const float*)d_in[0];
  const int*   captions = (const int*)d_in[1];
  const float* W_enc  = (const float*)d_in[2];
  const float* b_enc  = (const float*)d_in[3];
  const float* emb    = (const float*)d_in[4];
  const float* W_ih   = (const float*)d_in[5];
  const float* b_ih   = (const float*)d_in[6];
  const float* W_hh   = (const float*)d_in[7];
  const float* b_hh   = (const float*)d_in[8];
  const float* W_d2   = (const float*)d_in[9];
  const float* b_d2   = (const float*)d_in[10];
  const float* W_last = (const float*)d_in[11];
  const float* b_last = (const float*)d_in[12];
  float* out = (float*)d_out;

  char* ws = (char*)d_ws;
  size_t off = 0;
  auto alloc = [&](size_t bytes) -> void* {
    void* p = ws + off;
    off += (bytes + 255) & ~(size_t)255;
    return p;
  };
  unsigned short* xb     = (unsigned short*)alloc((size_t)MR_ * E_ * 2);       // time-major x, bf16
  unsigned short* Wb_ih  = (unsigned short*)alloc((size_t)4 * H_ * E_ * 2);
  unsigned short* Wb_hh  = (unsigned short*)alloc((size_t)4 * H_ * H_ * 2);
  unsigned short* Wb_d2t = (unsigned short*)alloc((size_t)D2_ * H_ * 2);       // (D2 x H)
  unsigned short* Wb_lt  = (unsigned short*)alloc((size_t)V_ * D2_ * 2);       // (V x D2)
  float*          G      = (float*)alloc((size_t)MR_ * 4 * H_ * 4);            // x@Wih^T + biases
  float*          lin    = (float*)alloc((size_t)B_ * 4 * H_ * 4);             // h@Whh^T
  float*          cst    = (float*)alloc((size_t)B_ * H_ * 4);
  unsigned short* hb     = (unsigned short*)alloc((size_t)B_ * H_ * 2);
  unsigned short* hsb    = (unsigned short*)alloc((size_t)MR_ * H_ * 2);       // b-major rows
  unsigned short* outb   = (unsigned short*)alloc((size_t)MR_ * D2_ * 2);      // b-major rows
  (void)in_sizes; (void)n_in; (void)out_size; (void)ws_size;

  // weight prep (inputs are restored before every call, so this runs every call)
  cvt_bf16<<<(4 * H_ * E_ / 4 + 255) / 256, 256, 0, stream>>>(W_ih, Wb_ih, 4 * H_ * E_ / 4);
  cvt_bf16<<<(4 * H_ * H_ / 4 + 255) / 256, 256, 0, stream>>>(W_hh, Wb_hh, 4 * H_ * H_ / 4);
  transpose_cvt<<<dim3(D2_ / 32, H_ / 32), 256, 0, stream>>>(W_d2, Wb_d2t, H_, D2_);
  transpose_cvt<<<dim3(V_ / 32, D2_ / 32), 256, 0, stream>>>(W_last, Wb_lt, D2_, V_);

  // build x (bf16): t=0 encoder GEMM, t=1..16 embedding gather
  encode<<<dim3(2, B_), 256, 0, stream>>>(features, W_enc, b_enc, xb);
  embed_k<<<dim3(T_ - 1, B_), 128, 0, stream>>>(captions, emb, xb);

  // G = x @ W_ih^T + b_ih + b_hh for all 2176 rows
  gemm_bt<0><<<dim3(4 * H_ / 128, MR_ / 128), 256, 0, stream>>>(xb, Wb_ih, G, b_ih, b_hh, 4 * H_, E_);

  // LSTM: t=0 uses h0=c0=0 (no recurrent GEMM)
  lstm_point<<<B_ * H_ / 256, 256, 0, stream>>>(G, nullptr, cst, hb, hsb, 0, 0);
  for (int t = 1; t < T_; t++) {
    gemm_bt<1><<<dim3(4 * H_ / 128, 1), 256, 0, stream>>>(hb, Wb_hh, lin, nullptr, nullptr, 4 * H_, H_);
    lstm_point<<<B_ * H_ / 256, 256, 0, stream>>>(G + (size_t)t * B_ * 4 * H_, lin, cst, hb, hsb, t, 1);
  }

  // out = relu(hs @ W_d2 + b_d2)  -> bf16, b-major rows
  gemm_bt<2><<<dim3(D2_ / 128, MR_ / 128), 256, 0, stream>>>(hsb, Wb_d2t, outb, b_d2, nullptr, D2_, H_);

  // logits = out @ W_last + b_last -> d_out (rows already b-major == (b*17+t))
  gemm_bt<3><<<dim3(V_ / 128, MR_ / 128), 256, 0, stream>>>(outb, Wb_lt, out, b_last, nullptr, V_, D2_);

  // softmax in place
  softmax_k<<<MR_, 1024, 0, stream>>>(out);
}

// Round 2
// 973.247 us; speedup vs baseline: 1.0503x; 1.0503x over previous
//
#include <hip/hip_runtime.h>
#include <hip/hip_bf16.h>

// ---- problem constants ----
#define B_   128
#define T_   17
#define E_   512
#define H_   512
#define V_   32000
#define D2_  1024
#define MR_  (B_*T_)   // 2176 rows = 17*128

typedef __attribute__((ext_vector_type(8))) short short8;   // 8 bf16 in 4 VGPRs
typedef __attribute__((ext_vector_type(4))) float f32x4;

__device__ __forceinline__ unsigned short f2b(float f) {   // fp32 -> bf16 RNE
  unsigned u = __float_as_uint(f);
  u += 0x7FFFu + ((u >> 16) & 1u);
  return (unsigned short)(u >> 16);
}
__device__ __forceinline__ float sigf(float x) { return 1.f / (1.f + __expf(-x)); }
__device__ __forceinline__ float tanhfast(float x) {
  x = fminf(fmaxf(x, -15.f), 15.f);
  float e = __expf(2.f * x);
  return (e - 1.f) / (e + 1.f);
}

// async global->LDS, 16B per lane. LDS dest is wave-uniform base + lane*16.
__device__ __forceinline__ void async16(const void* g, void* l) {
  __builtin_amdgcn_global_load_lds((const __attribute__((address_space(1))) unsigned int*)g,
                                   (__attribute__((address_space(3))) unsigned int*)l,
                                   16, 0, 0);
}

// ---------------------------------------------------------------------------
// bf16 MFMA GEMM: C[M x N] = A[M x K] * Bt[N x K]^T (+ epilogue)
// 128x128 tile, 4 waves. Grid: blockIdx.x = M-block (fastest) so N-groups
// share B-tiles in L2/L3. Swizzle key (row>>2)&3 -> 2-way-only LDS banking.
// EPI: 0 = f32, +permuted(bias0+bias1) (gates G, interleaved-gate cols)
//      2 = bf16 relu(+bias0)           3 = bf16 +bias0      4 = f32 +bias0
// ---------------------------------------------------------------------------
template<int EPI>
__global__ __launch_bounds__(256, 2)
void gemm_bt(const unsigned short* __restrict__ A,
             const unsigned short* __restrict__ Bt,
             void* __restrict__ C,
             const float* __restrict__ bias0,
             const float* __restrict__ bias1,
             int N, int K)
{
  __shared__ unsigned short sA[128 * 32];
  __shared__ unsigned short sB[128 * 32];

  const int tid  = threadIdx.x;
  const int lane = tid & 63;
  const int wave = tid >> 6;
  const int wm   = wave & 1;
  const int wn   = wave >> 1;
  const size_t bm = (size_t)blockIdx.x * 128;   // M fastest-varying
  const size_t bn = (size_t)blockIdx.y * 128;

  const int sRow   = wave * 32 + (lane >> 2);
  const int gchunk = (lane & 3) ^ ((sRow >> 2) & 3);   // (row>>2) same for sRow and sRow+16

  const unsigned short* gA  = A  + (bm + sRow)      * (size_t)K + gchunk * 8;
  const unsigned short* gA2 = A  + (bm + sRow + 16) * (size_t)K + gchunk * 8;
  const unsigned short* gB  = Bt + (bn + sRow)      * (size_t)K + gchunk * 8;
  const unsigned short* gB2 = Bt + (bn + sRow + 16) * (size_t)K + gchunk * 8;

  unsigned short* lA  = &sA[wave * 1024];
  unsigned short* lA2 = &sA[wave * 1024 + 512];
  unsigned short* lB  = &sB[wave * 1024];
  unsigned short* lB2 = &sB[wave * 1024 + 512];

  f32x4 acc[4][4] = {};
  const int fm = lane & 15;
  const int q  = lane >> 4;

  for (int kt = 0; kt < K; kt += 32) {
    async16(gA  + kt, lA);
    async16(gA2 + kt, lA2);
    async16(gB  + kt, lB);
    async16(gB2 + kt, lB2);
    __syncthreads();

    short8 af[4], bfv[4];
#pragma unroll
    for (int i = 0; i < 4; i++) {
      int ra = wm * 64 + i * 16 + fm;
      af[i]  = *(const short8*)&sA[ra * 32 + ((q ^ ((ra >> 2) & 3)) * 8)];
      int rb = wn * 64 + i * 16 + fm;
      bfv[i] = *(const short8*)&sB[rb * 32 + ((q ^ ((rb >> 2) & 3)) * 8)];
    }
#pragma unroll
    for (int i = 0; i < 4; i++)
#pragma unroll
      for (int j = 0; j < 4; j++)
        acc[i][j] = __builtin_amdgcn_mfma_f32_16x16x32_bf16(af[i], bfv[j], acc[i][j], 0, 0, 0);
    __syncthreads();
  }

  // C/D layout: col = lane&15, row = (lane>>4)*4 + reg
#pragma unroll
  for (int i = 0; i < 4; i++) {
#pragma unroll
    for (int j = 0; j < 4; j++) {
      size_t col = bn + wn * 64 + j * 16 + fm;
      float bv = 0.f;
      if constexpr (EPI == 0) {
        size_t oc = ((col & 3) << 9) + (col >> 2);   // un-permute gate col
        bv = bias0[oc] + bias1[oc];
      }
      if constexpr (EPI == 2 || EPI == 3 || EPI == 4) bv = bias0[col];
#pragma unroll
      for (int r = 0; r < 4; r++) {
        size_t row = bm + wm * 64 + i * 16 + q * 4 + r;
        float v = acc[i][j][r] + bv;
        if constexpr (EPI == 2) {
          v = v > 0.f ? v : 0.f;
          ((unsigned short*)C)[row * N + col] = f2b(v);
        } else if constexpr (EPI == 3) {
          ((unsigned short*)C)[row * N + col] = f2b(v);
        } else {
          ((float*)C)[row * N + col] = v;
        }
      }
    }
  }
}

// ---------------------------------------------------------------------------
// Fused LSTM step: gates = Gt + h_prev @ Whh^T (Whh rows gate-interleaved),
// pointwise -> c, h. 16 blocks (128 N-cols each = 32 complete units), BK=64.
// ---------------------------------------------------------------------------
__global__ __launch_bounds__(256)
void lstm_step(const unsigned short* __restrict__ hprev,  // 128x512 bf16
               const unsigned short* __restrict__ Whh,    // 2048x512 bf16, permuted rows
               const float* __restrict__ Gt,              // 128x2048 f32, permuted cols
               float* __restrict__ c,                     // 128x512 f32
               unsigned short* __restrict__ hout,         // 128x512 bf16
               unsigned short* __restrict__ hsb,          // b-major hs
               int t)
{
  __shared__ float gl[128 * 132];                       // 67.6 KB, ld=132 (bank-pad)
  unsigned short* sA = (unsigned short*)gl;             // 128x64 bf16 = 16 KB
  unsigned short* sB = (unsigned short*)(gl + 4096);    // 16 KB

  const int tid  = threadIdx.x;
  const int lane = tid & 63;
  const int wave = tid >> 6;
  const int wm   = wave & 1;
  const int wn   = wave >> 1;
  const int n0   = blockIdx.x * 128;

  // staging: 8 rows per async16 (8 chunks of 16B per row). row&7 == lane>>3.
  const int sR  = lane >> 3;
  const int gch = (lane & 7) ^ sR;                      // LDS(r,p) holds chunk p^(r&7)
  const size_t aoff = (size_t)(wave * 32 + sR) * 512 + gch * 8;
  const size_t boff = (size_t)(n0 + wave * 32 + sR) * 512 + gch * 8;

  f32x4 acc[4][4] = {};
  const int fm = lane & 15;
  const int q  = lane >> 4;

  for (int kt = 0; kt < 512; kt += 64) {
#pragma unroll
    for (int s = 0; s < 4; s++) {
      async16(hprev + aoff + s * 4096 + kt, sA + wave * 2048 + s * 512);
      async16(Whh   + boff + s * 4096 + kt, sB + wave * 2048 + s * 512);
    }
    __syncthreads();

    short8 af[2][4], bfv[2][4];
#pragma unroll
    for (int kk = 0; kk < 2; kk++) {
      int cch = kk * 4 + q;
#pragma unroll
      for (int i = 0; i < 4; i++) {
        int ra = wm * 64 + i * 16 + fm;
        af[kk][i]  = *(const short8*)&sA[ra * 64 + ((cch ^ (ra & 7)) * 8)];
        int rb = wn * 64 + i * 16 + fm;
        bfv[kk][i] = *(const short8*)&sB[rb * 64 + ((cch ^ (rb & 7)) * 8)];
      }
    }
#pragma unroll
    for (int kk = 0; kk < 2; kk++)
#pragma unroll
      for (int i = 0; i < 4; i++)
#pragma unroll
        for (int j = 0; j < 4; j++)
          acc[i][j] = __builtin_amdgcn_mfma_f32_16x16x32_bf16(af[kk][i], bfv[kk][j], acc[i][j], 0, 0, 0);
    __syncthreads();
  }

  // dump accumulators to LDS gate buffer
#pragma unroll
  for (int i = 0; i < 4; i++)
#pragma unroll
    for (int j = 0; j < 4; j++)
#pragma unroll
      for (int r = 0; r < 4; r++)
        gl[(wm * 64 + i * 16 + q * 4 + r) * 132 + wn * 64 + j * 16 + fm] = acc[i][j][r];
  __syncthreads();

  // pointwise: 128 rows x 32 local units
#pragma unroll
  for (int it = 0; it < 16; it++) {
    int p   = it * 256 + tid;
    int row = p >> 5;
    int ul  = p & 31;
    float4 a4 = *(float4*)&gl[row * 132 + ul * 4];
    float4 G4 = *(const float4*)&Gt[row * 2048 + n0 + ul * 4];
    float gi = a4.x + G4.x, gf = a4.y + G4.y, gg = a4.z + G4.z, go = a4.w + G4.w;
    int gu  = (n0 >> 2) + ul;
    int idx = row * 512 + gu;
    float cn = sigf(gf) * c[idx] + sigf(gi) * tanhfast(gg);
    c[idx] = cn;
    float hn = sigf(go) * tanhfast(cn);
    unsigned short h16 = f2b(hn);
    hout[idx] = h16;
    hsb[((size_t)row * T_ + t) * 512 + gu] = h16;
  }
}

// ---- t=0 pointwise (h0=c0=0): gates straight from permuted G[0] ----
__global__ void lstm_point0(const float* __restrict__ G0, float* __restrict__ c,
                            unsigned short* __restrict__ hb, unsigned short* __restrict__ hsb) {
  int idx = blockIdx.x * 256 + threadIdx.x;    // 128*512
  int b = idx >> 9, u = idx & 511;
  float4 g4 = ((const float4*)(G0 + (size_t)b * 2048))[u];
  float cn = sigf(g4.x) * tanhfast(g4.z);
  c[idx] = cn;
  float hn = sigf(g4.w) * tanhfast(cn);
  unsigned short h16 = f2b(hn);
  hb[idx] = h16;
  hsb[((size_t)b * T_ + 0) * 512 + u] = h16;
}

// ---- gate-interleave + bf16 convert: out row p=u*4+g <- in row g*512+u ----
__global__ void permute_cvt(const float* __restrict__ src, unsigned short* __restrict__ dst) {
  int p  = blockIdx.x;                          // 0..2047
  int ir = ((p & 3) << 9) + (p >> 2);
  float4 v = ((const float4*)(src + (size_t)ir * 512))[threadIdx.x];   // 128 thr
  ushort4 o;
  o.x = f2b(v.x); o.y = f2b(v.y); o.z = f2b(v.z); o.w = f2b(v.w);
  ((ushort4*)(dst + (size_t)p * 512))[threadIdx.x] = o;
}

// ---- fp32 KxN -> bf16 NxK transpose+convert ----
__global__ void transpose_cvt(const float* __restrict__ src, unsigned short* __restrict__ dst,
                              int K, int N) {
  __shared__ float tile[32][33];
  int n0 = blockIdx.x * 32, k0 = blockIdx.y * 32;
  int tcol = threadIdx.x & 31, trow = threadIdx.x >> 5;
  for (int r = trow; r < 32; r += 8)
    tile[r][tcol] = src[(size_t)(k0 + r) * N + n0 + tcol];
  __syncthreads();
  for (int r = trow; r < 32; r += 8)
    dst[(size_t)(n0 + r) * K + k0 + tcol] = f2b(tile[tcol][r]);
}

// ---- encoder row (t=0 of x) ----
__global__ __launch_bounds__(256) void encode(const float* __restrict__ features,
                                              const float* __restrict__ W_enc,
                                              const float* __restrict__ b_enc,
                                              unsigned short* __restrict__ xb) {
  __shared__ float fs[512];
  int b = blockIdx.y, e = blockIdx.x * 256 + threadIdx.x;
  fs[threadIdx.x]       = features[b * 512 + threadIdx.x];
  fs[threadIdx.x + 256] = features[b * 512 + threadIdx.x + 256];
  __syncthreads();
  float acc = 0.f;
#pragma unroll 8
  for (int k = 0; k < 512; k++) acc += fs[k] * W_enc[(size_t)k * 512 + e];
  xb[(size_t)b * 512 + e] = f2b(acc + b_enc[e]);
}

// ---- embedding gather (t=1..16 of x, time-major) ----
__global__ void embed_k(const int* __restrict__ captions, const float* __restrict__ emb,
                        unsigned short* __restrict__ xb) {
  int t = blockIdx.x + 1, b = blockIdx.y;
  int tok = captions[b * T_ + (t - 1)];
  float4 v = ((const float4*)(emb + (size_t)tok * 512))[threadIdx.x];
  ushort4 o;
  o.x = f2b(v.x); o.y = f2b(v.y); o.z = f2b(v.z); o.w = f2b(v.w);
  ((ushort4*)(xb + (size_t)(t * B_ + b) * 512))[threadIdx.x] = o;
}

// ---- softmax from bf16 logits -> f32 probs ----
__global__ __launch_bounds__(1024) void softmax_b(const unsigned short* __restrict__ lg,
                                                  float* __restrict__ out) {
  __shared__ float ps[1024];
  const uint4* r4 = (const uint4*)(lg + (size_t)blockIdx.x * V_);   // 4000 uint4/row
  float* orow = out + (size_t)blockIdx.x * V_;
  int tid = threadIdx.x;
  float v[4][8];
  float s = 0.f;
#pragma unroll
  for (int u = 0; u < 4; u++) {
    int i = u * 1024 + tid;
    if (i < 4000) {
      uint4 w = r4[i];
      unsigned a[4] = {w.x, w.y, w.z, w.w};
#pragma unroll
      for (int k = 0; k < 4; k++) {
        float lo = __uint_as_float(a[k] << 16);
        float hi = __uint_as_float(a[k] & 0xffff0000u);
        float e0 = __expf(lo), e1 = __expf(hi);
        v[u][2 * k] = e0; v[u][2 * k + 1] = e1;
        s += e0 + e1;
      }
    }
  }
  ps[tid] = s;
  __syncthreads();
  for (int o = 512; o > 0; o >>= 1) {
    if (tid < o) ps[tid] += ps[tid + o];
    __syncthreads();
  }
  float inv = 1.f / ps[0];
#pragma unroll
  for (int u = 0; u < 4; u++) {
    int i = u * 1024 + tid;
    if (i < 4000) {
      float4 o1 = {v[u][0] * inv, v[u][1] * inv, v[u][2] * inv, v[u][3] * inv};
      float4 o2 = {v[u][4] * inv, v[u][5] * inv, v[u][6] * inv, v[u][7] * inv};
      ((float4*)(orow + (size_t)i * 8))[0] = o1;
      ((float4*)(orow + (size_t)i * 8))[1] = o2;
    }
  }
}

// ---- fallback: in-place f32 softmax ----
__global__ __launch_bounds__(1024) void softmax_f(float* __restrict__ out) {
  __shared__ float ps[1024];
  float* r = out + (size_t)blockIdx.x * V_;
  int tid = threadIdx.x;
  float v[32];
  float s = 0.f;
#pragma unroll
  for (int u = 0; u < 32; u++) {
    int i = u * 1024 + tid;
    if (i < V_) { float e = __expf(r[i]); v[u] = e; s += e; }
  }
  ps[tid] = s;
  __syncthreads();
  for (int o = 512; o > 0; o >>= 1) {
    if (tid < o) ps[tid] += ps[tid + o];
    __syncthreads();
  }
  float inv = 1.f / ps[0];
#pragma unroll
  for (int u = 0; u < 32; u++) {
    int i = u * 1024 + tid;
    if (i < V_) r[i] = v[u] * inv;
  }
}

extern "C" void kernel_launch(void* const* d_in, const int* in_sizes, int n_in,
                              void* d_out, int out_size, void* d_ws, size_t ws_size,
                              hipStream_t stream) {
  const float* features = (const float*)d_in[0];
  const int*   captions = (const int*)d_in[1];
  const float* W_enc  = (const float*)d_in[2];
  const float* b_enc  = (const float*)d_in[3];
  const float* emb    = (const float*)d_in[4];
  const float* W_ih   = (const float*)d_in[5];
  const float* b_ih   = (const float*)d_in[6];
  const float* W_hh   = (const float*)d_in[7];
  const float* b_hh   = (const float*)d_in[8];
  const float* W_d2   = (const float*)d_in[9];
  const float* b_d2   = (const float*)d_in[10];
  const float* W_last = (const float*)d_in[11];
  const float* b_last = (const float*)d_in[12];
  float* out = (float*)d_out;

  char* ws = (char*)d_ws;
  size_t off = 0;
  auto alloc = [&](size_t bytes) -> void* {
    void* p = ws + off;
    off += (bytes + 255) & ~(size_t)255;
    return p;
  };
  unsigned short* xb     = (unsigned short*)alloc((size_t)MR_ * E_ * 2);       // time-major x
  unsigned short* Wb_ih  = (unsigned short*)alloc((size_t)4 * H_ * E_ * 2);    // permuted rows
  unsigned short* Wb_hh  = (unsigned short*)alloc((size_t)4 * H_ * H_ * 2);    // permuted rows
  unsigned short* Wb_d2t = (unsigned short*)alloc((size_t)D2_ * H_ * 2);
  unsigned short* Wb_lt  = (unsigned short*)alloc((size_t)V_ * D2_ * 2);
  float*          G      = (float*)alloc((size_t)MR_ * 4 * H_ * 4);            // permuted cols
  float*          cst    = (float*)alloc((size_t)B_ * H_ * 4);
  unsigned short* hb0    = (unsigned short*)alloc((size_t)B_ * H_ * 2);
  unsigned short* hb1    = (unsigned short*)alloc((size_t)B_ * H_ * 2);
  unsigned short* hsb    = (unsigned short*)alloc((size_t)MR_ * H_ * 2);       // b-major
  unsigned short* outb   = (unsigned short*)alloc((size_t)MR_ * D2_ * 2);      // b-major
  size_t off_base = off;
  unsigned short* lgb    = (unsigned short*)alloc((size_t)MR_ * V_ * 2);       // bf16 logits
  const bool bf16_logits = (off <= ws_size);
  (void)in_sizes; (void)n_in; (void)out_size; (void)off_base;

  // weight prep
  permute_cvt<<<2048, 128, 0, stream>>>(W_ih, Wb_ih);
  permute_cvt<<<2048, 128, 0, stream>>>(W_hh, Wb_hh);
  transpose_cvt<<<dim3(D2_ / 32, H_ / 32), 256, 0, stream>>>(W_d2, Wb_d2t, H_, D2_);

  // x (bf16, time-major)
  encode<<<dim3(2, B_), 256, 0, stream>>>(features, W_enc, b_enc, xb);
  embed_k<<<dim3(T_ - 1, B_), 128, 0, stream>>>(captions, emb, xb);

  // G = x @ Wb_ih^T + (b_ih + b_hh), gate-interleaved columns
  gemm_bt<0><<<dim3(MR_ / 128, 4 * H_ / 128), 256, 0, stream>>>(xb, Wb_ih, G, b_ih, b_hh, 4 * H_, E_);

  // LSTM chain (fused gemm+pointwise per step, ping-pong h buffers)
  lstm_point0<<<B_ * H_ / 256, 256, 0, stream>>>(G, cst, hb0, hsb);
  for (int t = 1; t < T_; t++) {
    unsigned short* hp = (t & 1) ? hb0 : hb1;
    unsigned short* hc = (t & 1) ? hb1 : hb0;
    lstm_step<<<16, 256, 0, stream>>>(hp, Wb_hh, G + (size_t)t * B_ * 4 * H_, cst, hc, hsb, t);
  }

  // W_last transpose late so Wb_lt is L3-warm for the big GEMM
  transpose_cvt<<<dim3(V_ / 32, D2_ / 32), 256, 0, stream>>>(W_last, Wb_lt, D2_, V_);

  // out = relu(hs @ W_d2 + b_d2) -> bf16 (b-major rows)
  gemm_bt<2><<<dim3(MR_ / 128, D2_ / 128), 256, 0, stream>>>(hsb, Wb_d2t, outb, b_d2, nullptr, D2_, H_);

  // logits = out @ W_last + b_last, then softmax
  if (bf16_logits) {
    gemm_bt<3><<<dim3(MR_ / 128, V_ / 128), 256, 0, stream>>>(outb, Wb_lt, lgb, b_last, nullptr, V_, D2_);
    softmax_b<<<MR_, 1024, 0, stream>>>(lgb, out);
  } else {
    gemm_bt<4><<<dim3(MR_ / 128, V_ / 128), 256, 0, stream>>>(outb, Wb_lt, out, b_last, nullptr, V_, D2_);
    softmax_f<<<MR_, 1024, 0, stream>>>(out);
  }
}

// Round 3
// 947.786 us; speedup vs baseline: 1.0785x; 1.0269x over previous
//
#include <hip/hip_runtime.h>
#include <hip/hip_bf16.h>

// ---- problem constants ----
#define B_   128
#define T_   17
#define E_   512
#define H_   512
#define V_   32000
#define D2_  1024
#define MR_  (B_*T_)   // 2176 rows = 17*128

typedef __attribute__((ext_vector_type(8))) short short8;   // 8 bf16 in 4 VGPRs
typedef __attribute__((ext_vector_type(4))) float f32x4;

__device__ __forceinline__ unsigned short f2b(float f) {   // fp32 -> bf16 RNE
  unsigned u = __float_as_uint(f);
  u += 0x7FFFu + ((u >> 16) & 1u);
  return (unsigned short)(u >> 16);
}
__device__ __forceinline__ float sigf(float x) { return 1.f / (1.f + __expf(-x)); }
__device__ __forceinline__ float tanhfast(float x) {
  x = fminf(fmaxf(x, -15.f), 15.f);
  float e = __expf(2.f * x);
  return (e - 1.f) / (e + 1.f);
}

// async global->LDS, 16B per lane. LDS dest is wave-uniform base + lane*16.
__device__ __forceinline__ void async16(const void* g, void* l) {
  __builtin_amdgcn_global_load_lds((const __attribute__((address_space(1))) unsigned int*)g,
                                   (__attribute__((address_space(3))) unsigned int*)l,
                                   16, 0, 0);
}

// ---------------------------------------------------------------------------
// bf16 MFMA GEMM: C[M x N] = A[M x K] * Bt[N x K]^T (+ epilogue)
// 128x128 tile, 4 waves, 1-D grid, M-block = f % nbm (fastest).
// SWZ=1: XCD-slab remap (launch 8*ceil(nwork/8) blocks): f' = (f&7)*per + f>>3
//   -> each XCD owns a contiguous run of N-groups, M inner => B-tile L2-resident.
// EPI: 0 = f32 +permuted(bias0+bias1)   2 = bf16 relu(+bias0)
//      3 = bf16 +bias0                  4 = f32 +bias0
// ---------------------------------------------------------------------------
template<int EPI, int SWZ>
__global__ __launch_bounds__(256, 2)
void gemm_bt(const unsigned short* __restrict__ A,
             const unsigned short* __restrict__ Bt,
             void* __restrict__ C,
             const float* __restrict__ bias0,
             const float* __restrict__ bias1,
             int N, int K, int nbm, int nwork)
{
  __shared__ unsigned short sA[128 * 32];
  __shared__ unsigned short sB[128 * 32];

  int f = blockIdx.x;
  if constexpr (SWZ) {
    int per = (nwork + 7) >> 3;
    f = (f & 7) * per + (f >> 3);
    if (f >= nwork) return;
  }
  const size_t bm = (size_t)(f % nbm) * 128;
  const size_t bn = (size_t)(f / nbm) * 128;

  const int tid  = threadIdx.x;
  const int lane = tid & 63;
  const int wave = tid >> 6;
  const int wm   = wave & 1;
  const int wn   = wave >> 1;

  const int sRow   = wave * 32 + (lane >> 2);
  const int gchunk = (lane & 3) ^ ((sRow >> 2) & 3);

  const unsigned short* gA  = A  + (bm + sRow)      * (size_t)K + gchunk * 8;
  const unsigned short* gA2 = A  + (bm + sRow + 16) * (size_t)K + gchunk * 8;
  const unsigned short* gB  = Bt + (bn + sRow)      * (size_t)K + gchunk * 8;
  const unsigned short* gB2 = Bt + (bn + sRow + 16) * (size_t)K + gchunk * 8;

  unsigned short* lA  = &sA[wave * 1024];
  unsigned short* lA2 = &sA[wave * 1024 + 512];
  unsigned short* lB  = &sB[wave * 1024];
  unsigned short* lB2 = &sB[wave * 1024 + 512];

  f32x4 acc[4][4] = {};
  const int fm = lane & 15;
  const int q  = lane >> 4;

  for (int kt = 0; kt < K; kt += 32) {
    async16(gA  + kt, lA);
    async16(gA2 + kt, lA2);
    async16(gB  + kt, lB);
    async16(gB2 + kt, lB2);
    __syncthreads();

    short8 af[4], bfv[4];
#pragma unroll
    for (int i = 0; i < 4; i++) {
      int ra = wm * 64 + i * 16 + fm;
      af[i]  = *(const short8*)&sA[ra * 32 + ((q ^ ((ra >> 2) & 3)) * 8)];
      int rb = wn * 64 + i * 16 + fm;
      bfv[i] = *(const short8*)&sB[rb * 32 + ((q ^ ((rb >> 2) & 3)) * 8)];
    }
#pragma unroll
    for (int i = 0; i < 4; i++)
#pragma unroll
      for (int j = 0; j < 4; j++)
        acc[i][j] = __builtin_amdgcn_mfma_f32_16x16x32_bf16(af[i], bfv[j], acc[i][j], 0, 0, 0);
    __syncthreads();
  }

  // C/D layout: col = lane&15, row = (lane>>4)*4 + reg
#pragma unroll
  for (int i = 0; i < 4; i++) {
#pragma unroll
    for (int j = 0; j < 4; j++) {
      size_t col = bn + wn * 64 + j * 16 + fm;
      float bv = 0.f;
      if constexpr (EPI == 0) {
        size_t oc = ((col & 3) << 9) + (col >> 2);   // un-permute gate col
        bv = bias0[oc] + bias1[oc];
      }
      if constexpr (EPI == 2 || EPI == 3 || EPI == 4) bv = bias0[col];
#pragma unroll
      for (int r = 0; r < 4; r++) {
        size_t row = bm + wm * 64 + i * 16 + q * 4 + r;
        float v = acc[i][j][r] + bv;
        if constexpr (EPI == 2) {
          v = v > 0.f ? v : 0.f;
          ((unsigned short*)C)[row * N + col] = f2b(v);
        } else if constexpr (EPI == 3) {
          ((unsigned short*)C)[row * N + col] = f2b(v);
        } else {
          ((float*)C)[row * N + col] = v;
        }
      }
    }
  }
}

// ---------------------------------------------------------------------------
// Fused LSTM step: gates = Gt + h_prev @ Whh^T (rows gate-interleaved), then
// pointwise -> c, h. 16 blocks x 128 cols. BK=256 => only 2 K-iters (fewer
// barrier drains on the serial chain). LDS: 2x64KB staging, gate buf aliased.
// ---------------------------------------------------------------------------
__global__ __launch_bounds__(256)
void lstm_step(const unsigned short* __restrict__ hprev,  // 128x512 bf16
               const unsigned short* __restrict__ Whh,    // 2048x512 bf16 permuted
               const float* __restrict__ Gt,              // 128x2048 f32 permuted
               float* __restrict__ c,                     // 128x512 f32
               unsigned short* __restrict__ hout,         // 128x512 bf16
               unsigned short* __restrict__ hsb,          // b-major hs
               int t)
{
  __shared__ char smem[131072];                       // 128 KB
  unsigned short* sA = (unsigned short*)smem;         // 128x256 bf16
  unsigned short* sB = (unsigned short*)(smem + 65536);
  float* gl = (float*)smem;                           // 128x132 f32 (aliased)

  const int tid  = threadIdx.x;
  const int lane = tid & 63;
  const int wave = tid >> 6;
  const int wm   = wave & 1;
  const int wn   = wave >> 1;
  const int n0   = blockIdx.x * 128;

  const int lr = lane >> 5;     // row parity within instruction (2 rows x 32 chunks)
  const int lp = lane & 31;     // LDS chunk position

  f32x4 acc[4][4] = {};
  const int fm = lane & 15;
  const int q  = lane >> 4;

  for (int kt = 0; kt < 512; kt += 256) {
#pragma unroll
    for (int s = 0; s < 16; s++) {
      int row = wave * 32 + s * 2 + lr;           // row within 128-tile
      int gch = lp ^ (row & 7);                   // swizzled global chunk
      async16(hprev + (size_t)row * 512 + kt + gch * 8,
              sA + wave * 8192 + s * 512 + lane * 8);
      async16(Whh + (size_t)(n0 + row) * 512 + kt + gch * 8,
              sB + wave * 8192 + s * 512 + lane * 8);
    }
    __syncthreads();

#pragma unroll
    for (int kk = 0; kk < 8; kk++) {
      int ch = kk * 4 + q;
      short8 af[4], bfv[4];
#pragma unroll
      for (int i = 0; i < 4; i++) {
        int ra = wm * 64 + i * 16 + fm;
        af[i]  = *(const short8*)&sA[ra * 256 + ((ch ^ (ra & 7)) * 8)];
        int rb = wn * 64 + i * 16 + fm;
        bfv[i] = *(const short8*)&sB[rb * 256 + ((ch ^ (rb & 7)) * 8)];
      }
#pragma unroll
      for (int i = 0; i < 4; i++)
#pragma unroll
        for (int j = 0; j < 4; j++)
          acc[i][j] = __builtin_amdgcn_mfma_f32_16x16x32_bf16(af[i], bfv[j], acc[i][j], 0, 0, 0);
    }
    __syncthreads();
  }

  // accumulators -> aliased LDS gate buffer (ld=132 breaks bank alignment)
#pragma unroll
  for (int i = 0; i < 4; i++)
#pragma unroll
    for (int j = 0; j < 4; j++)
#pragma unroll
      for (int r = 0; r < 4; r++)
        gl[(wm * 64 + i * 16 + q * 4 + r) * 132 + wn * 64 + j * 16 + fm] = acc[i][j][r];
  __syncthreads();

  // pointwise: 128 rows x 32 local units (gates interleaved i,f,g,o per unit)
#pragma unroll
  for (int it = 0; it < 16; it++) {
    int p   = it * 256 + tid;
    int row = p >> 5;
    int ul  = p & 31;
    float4 a4 = *(float4*)&gl[row * 132 + ul * 4];
    float4 G4 = *(const float4*)&Gt[row * 2048 + n0 + ul * 4];
    float gi = a4.x + G4.x, gf = a4.y + G4.y, gg = a4.z + G4.z, go = a4.w + G4.w;
    int gu  = (n0 >> 2) + ul;
    int idx = row * 512 + gu;
    float cn = sigf(gf) * c[idx] + sigf(gi) * tanhfast(gg);
    c[idx] = cn;
    float hn = sigf(go) * tanhfast(cn);
    unsigned short h16 = f2b(hn);
    hout[idx] = h16;
    hsb[((size_t)row * T_ + t) * 512 + gu] = h16;
  }
}

// ---- t=0 pointwise (h0=c0=0) ----
__global__ void lstm_point0(const float* __restrict__ G0, float* __restrict__ c,
                            unsigned short* __restrict__ hb, unsigned short* __restrict__ hsb) {
  int idx = blockIdx.x * 256 + threadIdx.x;    // 128*512
  int b = idx >> 9, u = idx & 511;
  float4 g4 = ((const float4*)(G0 + (size_t)b * 2048))[u];
  float cn = sigf(g4.x) * tanhfast(g4.z);
  c[idx] = cn;
  float hn = sigf(g4.w) * tanhfast(cn);
  unsigned short h16 = f2b(hn);
  hb[idx] = h16;
  hsb[((size_t)b * T_ + 0) * 512 + u] = h16;
}

// ---- gate-interleave + bf16 convert for both W_ih and W_hh in one launch ----
__global__ void permute_cvt2(const float* __restrict__ Wih, const float* __restrict__ Whh,
                             unsigned short* __restrict__ dih, unsigned short* __restrict__ dhh) {
  int p = blockIdx.x;                           // 0..4095
  const float* src = (p < 2048) ? Wih : Whh;
  unsigned short* dst = (p < 2048) ? dih : dhh;
  int pp = p & 2047;
  int ir = ((pp & 3) << 9) + (pp >> 2);
  float4 v = ((const float4*)(src + (size_t)ir * 512))[threadIdx.x];   // 128 thr
  ushort4 o;
  o.x = f2b(v.x); o.y = f2b(v.y); o.z = f2b(v.z); o.w = f2b(v.w);
  ((ushort4*)(dst + (size_t)p * 512))[threadIdx.x] = o;
}

// ---- fp32 KxN -> bf16 NxK transpose+convert ----
__global__ void transpose_cvt(const float* __restrict__ src, unsigned short* __restrict__ dst,
                              int K, int N) {
  __shared__ float tile[32][33];
  int n0 = blockIdx.x * 32, k0 = blockIdx.y * 32;
  int tcol = threadIdx.x & 31, trow = threadIdx.x >> 5;
  for (int r = trow; r < 32; r += 8)
    tile[r][tcol] = src[(size_t)(k0 + r) * N + n0 + tcol];
  __syncthreads();
  for (int r = trow; r < 32; r += 8)
    dst[(size_t)(n0 + r) * K + k0 + tcol] = f2b(tile[tcol][r]);
}

// ---- encoder row (t=0 of x) ----
__global__ __launch_bounds__(256) void encode(const float* __restrict__ features,
                                              const float* __restrict__ W_enc,
                                              const float* __restrict__ b_enc,
                                              unsigned short* __restrict__ xb) {
  __shared__ float fs[512];
  int b = blockIdx.y, e = blockIdx.x * 256 + threadIdx.x;
  fs[threadIdx.x]       = features[b * 512 + threadIdx.x];
  fs[threadIdx.x + 256] = features[b * 512 + threadIdx.x + 256];
  __syncthreads();
  float acc = 0.f;
#pragma unroll 8
  for (int k = 0; k < 512; k++) acc += fs[k] * W_enc[(size_t)k * 512 + e];
  xb[(size_t)b * 512 + e] = f2b(acc + b_enc[e]);
}

// ---- embedding gather (t=1..16 of x, time-major) ----
__global__ void embed_k(const int* __restrict__ captions, const float* __restrict__ emb,
                        unsigned short* __restrict__ xb) {
  int t = blockIdx.x + 1, b = blockIdx.y;
  int tok = captions[b * T_ + (t - 1)];
  float4 v = ((const float4*)(emb + (size_t)tok * 512))[threadIdx.x];
  ushort4 o;
  o.x = f2b(v.x); o.y = f2b(v.y); o.z = f2b(v.z); o.w = f2b(v.w);
  ((ushort4*)(xb + (size_t)(t * B_ + b) * 512))[threadIdx.x] = o;
}

// ---- softmax from bf16 logits -> f32 probs ----
__global__ __launch_bounds__(1024) void softmax_b(const unsigned short* __restrict__ lg,
                                                  float* __restrict__ out) {
  __shared__ float ps[1024];
  const uint4* r4 = (const uint4*)(lg + (size_t)blockIdx.x * V_);   // 4000 uint4/row
  float* orow = out + (size_t)blockIdx.x * V_;
  int tid = threadIdx.x;
  float v[4][8];
  float s = 0.f;
#pragma unroll
  for (int u = 0; u < 4; u++) {
    int i = u * 1024 + tid;
    if (i < 4000) {
      uint4 w = r4[i];
      unsigned a[4] = {w.x, w.y, w.z, w.w};
#pragma unroll
      for (int k = 0; k < 4; k++) {
        float lo = __uint_as_float(a[k] << 16);
        float hi = __uint_as_float(a[k] & 0xffff0000u);
        float e0 = __expf(lo), e1 = __expf(hi);
        v[u][2 * k] = e0; v[u][2 * k + 1] = e1;
        s += e0 + e1;
      }
    }
  }
  ps[tid] = s;
  __syncthreads();
  for (int o = 512; o > 0; o >>= 1) {
    if (tid < o) ps[tid] += ps[tid + o];
    __syncthreads();
  }
  float inv = 1.f / ps[0];
#pragma unroll
  for (int u = 0; u < 4; u++) {
    int i = u * 1024 + tid;
    if (i < 4000) {
      float4 o1 = {v[u][0] * inv, v[u][1] * inv, v[u][2] * inv, v[u][3] * inv};
      float4 o2 = {v[u][4] * inv, v[u][5] * inv, v[u][6] * inv, v[u][7] * inv};
      ((float4*)(orow + (size_t)i * 8))[0] = o1;
      ((float4*)(orow + (size_t)i * 8))[1] = o2;
    }
  }
}

// ---- fallback: in-place f32 softmax ----
__global__ __launch_bounds__(1024) void softmax_f(float* __restrict__ out) {
  __shared__ float ps[1024];
  float* r = out + (size_t)blockIdx.x * V_;
  int tid = threadIdx.x;
  float v[32];
  float s = 0.f;
#pragma unroll
  for (int u = 0; u < 32; u++) {
    int i = u * 1024 + tid;
    if (i < V_) { float e = __expf(r[i]); v[u] = e; s += e; }
  }
  ps[tid] = s;
  __syncthreads();
  for (int o = 512; o > 0; o >>= 1) {
    if (tid < o) ps[tid] += ps[tid + o];
    __syncthreads();
  }
  float inv = 1.f / ps[0];
#pragma unroll
  for (int u = 0; u < 32; u++) {
    int i = u * 1024 + tid;
    if (i < V_) r[i] = v[u] * inv;
  }
}

extern "C" void kernel_launch(void* const* d_in, const int* in_sizes, int n_in,
                              void* d_out, int out_size, void* d_ws, size_t ws_size,
                              hipStream_t stream) {
  const float* features = (const float*)d_in[0];
  const int*   captions = (const int*)d_in[1];
  const float* W_enc  = (const float*)d_in[2];
  const float* b_enc  = (const float*)d_in[3];
  const float* emb    = (const float*)d_in[4];
  const float* W_ih   = (const float*)d_in[5];
  const float* b_ih   = (const float*)d_in[6];
  const float* W_hh   = (const float*)d_in[7];
  const float* b_hh   = (const float*)d_in[8];
  const float* W_d2   = (const float*)d_in[9];
  const float* b_d2   = (const float*)d_in[10];
  const float* W_last = (const float*)d_in[11];
  const float* b_last = (const float*)d_in[12];
  float* out = (float*)d_out;

  char* ws = (char*)d_ws;
  size_t off = 0;
  auto alloc = [&](size_t bytes) -> void* {
    void* p = ws + off;
    off += (bytes + 255) & ~(size_t)255;
    return p;
  };
  unsigned short* xb     = (unsigned short*)alloc((size_t)MR_ * E_ * 2);
  unsigned short* Wb_ih  = (unsigned short*)alloc((size_t)4 * H_ * E_ * 2);
  unsigned short* Wb_hh  = (unsigned short*)alloc((size_t)4 * H_ * H_ * 2);
  unsigned short* Wb_d2t = (unsigned short*)alloc((size_t)D2_ * H_ * 2);
  unsigned short* Wb_lt  = (unsigned short*)alloc((size_t)V_ * D2_ * 2);
  float*          G      = (float*)alloc((size_t)MR_ * 4 * H_ * 4);
  float*          cst    = (float*)alloc((size_t)B_ * H_ * 4);
  unsigned short* hb0    = (unsigned short*)alloc((size_t)B_ * H_ * 2);
  unsigned short* hb1    = (unsigned short*)alloc((size_t)B_ * H_ * 2);
  unsigned short* hsb    = (unsigned short*)alloc((size_t)MR_ * H_ * 2);
  unsigned short* outb   = (unsigned short*)alloc((size_t)MR_ * D2_ * 2);
  unsigned short* lgb    = (unsigned short*)alloc((size_t)MR_ * V_ * 2);
  const bool bf16_logits = (off <= ws_size);
  (void)in_sizes; (void)n_in; (void)out_size;

  // weight prep
  permute_cvt2<<<4096, 128, 0, stream>>>(W_ih, W_hh, Wb_ih, Wb_hh);
  transpose_cvt<<<dim3(D2_ / 32, H_ / 32), 256, 0, stream>>>(W_d2, Wb_d2t, H_, D2_);

  // x (bf16, time-major)
  encode<<<dim3(2, B_), 256, 0, stream>>>(features, W_enc, b_enc, xb);
  embed_k<<<dim3(T_ - 1, B_), 128, 0, stream>>>(captions, emb, xb);

  // G = x @ Wb_ih^T + (b_ih + b_hh), gate-interleaved columns
  gemm_bt<0, 0><<<17 * 16, 256, 0, stream>>>(xb, Wb_ih, G, b_ih, b_hh, 4 * H_, E_, 17, 17 * 16);

  // LSTM chain (fused, ping-pong h buffers)
  lstm_point0<<<B_ * H_ / 256, 256, 0, stream>>>(G, cst, hb0, hsb);
  for (int t = 1; t < T_; t++) {
    unsigned short* hp = (t & 1) ? hb0 : hb1;
    unsigned short* hc = (t & 1) ? hb1 : hb0;
    lstm_step<<<16, 256, 0, stream>>>(hp, Wb_hh, G + (size_t)t * B_ * 4 * H_, cst, hc, hsb, t);
  }

  // W_last transpose late so Wb_lt is L2/L3-warm for the big GEMM
  transpose_cvt<<<dim3(V_ / 32, D2_ / 32), 256, 0, stream>>>(W_last, Wb_lt, D2_, V_);

  // out = relu(hs @ W_d2 + b_d2) -> bf16 (b-major rows)
  gemm_bt<2, 0><<<17 * 8, 256, 0, stream>>>(hsb, Wb_d2t, outb, b_d2, nullptr, D2_, H_, 17, 17 * 8);

  // logits = out @ W_last + b_last (XCD-slab swizzled), then softmax
  const int nwork = 17 * (V_ / 128);               // 4250
  const int per   = (nwork + 7) / 8;               // 532
  if (bf16_logits) {
    gemm_bt<3, 1><<<8 * per, 256, 0, stream>>>(outb, Wb_lt, lgb, b_last, nullptr, V_, D2_, 17, nwork);
    softmax_b<<<MR_, 1024, 0, stream>>>(lgb, out);
  } else {
    gemm_bt<4, 1><<<8 * per, 256, 0, stream>>>(outb, Wb_lt, out, b_last, nullptr, V_, D2_, 17, nwork);
    softmax_f<<<MR_, 1024, 0, stream>>>(out);
  }
}